// Round 19
// baseline (485.212 us; speedup 1.0000x reference)
//
#include <hip/hip_runtime.h>
#include <hip/hip_bf16.h>
#include <math.h>

typedef __bf16 bf16_t;
typedef __bf16 bf16x8 __attribute__((ext_vector_type(8)));
typedef float f32x4 __attribute__((ext_vector_type(4)));

#define AS1 __attribute__((address_space(1)))
#define AS3 __attribute__((address_space(3)))

static constexpr int S_  = 2048;
static constexpr int HID = 4096;
static constexpr int NH  = 32;
static constexpr int HD  = 128;
static constexpr int N3  = 3 * HID;           // 12288
static constexpr float SC2 = 0.12751674581f;  // (1/sqrt(128)) * log2(e)
static constexpr float THR = 11.0f;           // defer-max threshold

// ---------------- fp32 -> bf16 convert (vectorized) ----------------
__global__ void cvt_f32_bf16(const float* __restrict__ in, bf16_t* __restrict__ out, int n4) {
  int i = blockIdx.x * blockDim.x + threadIdx.x;
  if (i >= n4) return;
  float4 v = ((const float4*)in)[i];
  union { bf16_t h[4]; short4 s4; } u;
  u.h[0] = (bf16_t)v.x; u.h[1] = (bf16_t)v.y; u.h[2] = (bf16_t)v.z; u.h[3] = (bf16_t)v.w;
  ((short4*)out)[i] = u.s4;
}

// ------- transpose + convert: in[R][C] f32 -> out[C][R] bf16, 64x64 tile -------
__global__ __launch_bounds__(256) void transcvt64(
    const float* __restrict__ in, bf16_t* __restrict__ out, int R, int C) {
  __shared__ float t[64][65];
  const int r0 = blockIdx.y * 64, c0 = blockIdx.x * 64;
  const int tid = threadIdx.x;
  const int rr = tid >> 4, c4 = (tid & 15) * 4;
#pragma unroll
  for (int it = 0; it < 4; ++it) {
    float4 v = *(const float4*)&in[(size_t)(r0 + rr + it * 16) * C + c0 + c4];
    t[rr + it * 16][c4 + 0] = v.x;
    t[rr + it * 16][c4 + 1] = v.y;
    t[rr + it * 16][c4 + 2] = v.z;
    t[rr + it * 16][c4 + 3] = v.w;
  }
  __syncthreads();
  const int cc = tid >> 3, r8 = (tid & 7) * 8;
#pragma unroll
  for (int it = 0; it < 2; ++it) {
    const int c = cc + it * 32;
    bf16x8 w;
#pragma unroll
    for (int j = 0; j < 8; ++j) w[j] = (bf16_t)t[r8 + j][c];
    *(bf16x8*)&out[(size_t)(c0 + c) * R + r0 + r8] = w;
  }
}

// ------- per-head V transpose: qkv[s][2*HID + h*HD + d] -> vt[(h*HD+d)*S + s] -------
__global__ void vtrans(const bf16_t* __restrict__ qkv, bf16_t* __restrict__ vt) {
  __shared__ bf16_t t[32][33];
  int h = blockIdx.z;
  int s0 = blockIdx.x * 32, d0 = blockIdx.y * 32;
  int tx = threadIdx.x, ty = threadIdx.y;
#pragma unroll
  for (int i = 0; i < 32; i += 8)
    t[ty + i][tx] = qkv[(size_t)(s0 + ty + i) * N3 + 2 * HID + h * HD + d0 + tx];
  __syncthreads();
#pragma unroll
  for (int i = 0; i < 32; i += 8)
    vt[(size_t)(h * HD + d0 + ty + i) * S_ + s0 + tx] = t[tx][ty + i];
}

// ====== gemm_w: 256x128 tile, 4 waves (2Mx2N) of 128x64, ring-3, persistent ======
// R19: fragment double-buffer READ-AHEAD.  Ledger fact: vmcnt(6) before barrier(t)
// retires stage(t+1) in EVERY wave -> after barrier(t), slot(t+1) is fully resident.
// So slot(t+1)'s 12 ds_reads are issued right after barrier(t), interleaved with
// MFMA(t) (independent regs).  Pair-unrolled body with named fA/fB (rule 20).
// RAW: slot(t+1) validated at barrier(t).  WAR: stage(t+3)->slot(t) issues after
// barrier(t+1); reads of slot(t) completed at step-t's lgkm0 (pre-barrier).  Tails:
// vmcnt(0) at t=NT-2; fB's reads covered by compiler reg-dep waits at last MFMA.
__global__ __launch_bounds__(256, 2) void gemm_w(
    const bf16_t* __restrict__ A, const bf16_t* __restrict__ BT,
    const float* __restrict__ bias, bf16_t* __restrict__ C,
    int M, int N, int K, int ntiles) {
  extern __shared__ char smem[];
  const int tid = threadIdx.x;
  const int wv = tid >> 6, ln = tid & 63;
  const int lr = ln & 15, lg = ln >> 4;
  const int wm = wv >> 1, wn = wv & 1;

  const int nx = N >> 7;
  const int chunk = ntiles >> 3;  // ntiles % 8 == 0

  const int lrow = wv * 16 + (ln >> 2);
  const int lcol = ((ln & 3) << 3) ^ ((ln & 32) >> 1);
  const size_t row64 = (size_t)64 * K;
  const int sw = (lr & 8) << 2;
  const int aoff = (wm * 128 + lr) * 64 + ((lg * 16) ^ sw);
  const int boff = (wn * 64 + lr) * 64 + ((lg * 16) ^ sw);
  const int NT = K >> 5;  // 128

#define VMC6() asm volatile("s_waitcnt vmcnt(6)" ::: "memory")
#define VMC0() asm volatile("s_waitcnt vmcnt(0)" ::: "memory")
#define LGKM0() asm volatile("s_waitcnt lgkmcnt(0)" ::: "memory")
#define BARW() __builtin_amdgcn_s_barrier()
#define READF(SB, F)                                                       \
  _Pragma("unroll") for (int mi = 0; mi < 8; ++mi)                         \
      F[mi] = *(const bf16x8*)((SB) + aoff + mi * 1024);                   \
  _Pragma("unroll") for (int ni = 0; ni < 4; ++ni)                         \
      F[8 + ni] = *(const bf16x8*)((SB) + 16384 + boff + ni * 1024)
#define MFMAC(F)                                                           \
  __builtin_amdgcn_s_setprio(1);                                           \
  _Pragma("unroll") for (int mi = 0; mi < 8; ++mi)                         \
  _Pragma("unroll") for (int ni = 0; ni < 4; ++ni)                         \
      acc[mi][ni] = __builtin_amdgcn_mfma_f32_16x16x32_bf16(               \
          F[mi], F[8 + ni], acc[mi][ni], 0, 0, 0);                         \
  __builtin_amdgcn_s_setprio(0)

  for (int tt = blockIdx.x; tt < ntiles; tt += gridDim.x) {
    const int wg = (tt & 7) * chunk + (tt >> 3);  // XCD-contiguous chunks
    const int m0 = (wg / nx) * 256, n0 = (wg % nx) * 128;

    const bf16_t* gA = A + (size_t)(m0 + lrow) * K + lcol;
    const bf16_t* gB = BT + (size_t)(n0 + lrow) * K + lcol;

    // stage tile T (6 loads/wave) into slot S
    auto STGT = [&](int T, int S) {
      char* sb = smem + S * 24576 + wv * 1024;
#pragma unroll
      for (int i = 0; i < 4; ++i)
        __builtin_amdgcn_global_load_lds((const AS1 void*)(gA + i * row64 + T * 32),
                                         (AS3 void*)(sb + i * 4096), 16, 0, 0);
#pragma unroll
      for (int j = 0; j < 2; ++j)
        __builtin_amdgcn_global_load_lds((const AS1 void*)(gB + j * row64 + T * 32),
                                         (AS3 void*)(sb + 16384 + j * 4096), 16, 0, 0);
    };

    f32x4 acc[8][4] = {};
    bf16x8 fA[12], fB[12];

    // prologue: stage t0->s0, t1->s1; vmcnt(6) retires t0; read slot0 -> fA
    STGT(0, 0);
    STGT(1, 1);
    VMC6();
    BARW();
    READF(smem, fA);

    int sc = 0;  // slot(t) for even t
    for (int t = 0; t < NT - 2; t += 2) {
      int s1 = sc + 1; if (s1 > 2) s1 -= 3;
      int s2 = sc + 2; if (s2 > 2) s2 -= 3;
      // step t: stage(t+2)->s2; retire stage(t+1); barrier; read s1 under MFMA(fA)
      STGT(t + 2, s2);
      VMC6(); LGKM0();
      BARW();
      READF(smem + s1 * 24576, fB);
      MFMAC(fA);
      // step t+1: stage(t+3)->sc; retire stage(t+2); barrier; read s2 under MFMA(fB)
      STGT(t + 3, sc);
      VMC6(); LGKM0();
      BARW();
      READF(smem + s2 * 24576, fA);
      MFMAC(fB);
      sc = s2;
    }
    // t = NT-2: retire stage(NT-1); read its slot under MFMA(fA)
    {
      int s1 = sc + 1; if (s1 > 2) s1 -= 3;
      VMC0(); LGKM0();
      BARW();
      READF(smem + s1 * 24576, fB);
      MFMAC(fA);
      // t = NT-1: compiler reg-dep waits fB's reads
      MFMAC(fB);
    }

    // epilogue
#pragma unroll
    for (int mi = 0; mi < 8; ++mi)
#pragma unroll
      for (int ni = 0; ni < 4; ++ni) {
        const int col = n0 + wn * 64 + ni * 16 + lr;
        const float bv = bias[col];
#pragma unroll
        for (int i = 0; i < 4; ++i) {
          const int row = m0 + wm * 128 + mi * 16 + lg * 4 + i;
          C[(size_t)row * N + col] = (bf16_t)(acc[mi][ni][i] + bv);
        }
      }
  }
#undef VMC6
#undef VMC0
#undef LGKM0
#undef BARW
#undef READF
#undef MFMAC
}

// ====== 256x128-tile GEMM, 8 waves of 64x64, ring-3, persistent (out-proj) ======
template <bool STG, int VMC>
__device__ __forceinline__ void tile_step(
    const char* slot, int aoff, int boff,
    const bf16_t* gA, const bf16_t* gB, int kst, size_t skA,
    char* stg_dst, f32x4 (&acc)[4][4]) {
  bf16x8 a[4], b[4];
#pragma unroll
  for (int mi = 0; mi < 4; ++mi) a[mi] = *(const bf16x8*)(slot + aoff + mi * 1024);
#pragma unroll
  for (int ni = 0; ni < 4; ++ni) b[ni] = *(const bf16x8*)(slot + 16384 + boff + ni * 1024);
  if constexpr (STG) {
    __builtin_amdgcn_global_load_lds((const AS1 void*)(gA + kst), (AS3 void*)(stg_dst), 16, 0, 0);
    __builtin_amdgcn_global_load_lds((const AS1 void*)(gA + skA + kst), (AS3 void*)(stg_dst + 8192), 16, 0, 0);
    __builtin_amdgcn_global_load_lds((const AS1 void*)(gB + kst), (AS3 void*)(stg_dst + 16384), 16, 0, 0);
  }
  if constexpr (VMC == 3)      asm volatile("s_waitcnt vmcnt(3)" ::: "memory");
  else if constexpr (VMC == 0) asm volatile("s_waitcnt vmcnt(0)" ::: "memory");
  asm volatile("s_waitcnt lgkmcnt(0)" ::: "memory");
  __builtin_amdgcn_s_barrier();
  __builtin_amdgcn_s_setprio(1);
#pragma unroll
  for (int mi = 0; mi < 4; ++mi)
#pragma unroll
    for (int ni = 0; ni < 4; ++ni)
      acc[mi][ni] = __builtin_amdgcn_mfma_f32_16x16x32_bf16(a[mi], b[ni], acc[mi][ni], 0, 0, 0);
  __builtin_amdgcn_s_setprio(0);
}

template <typename OutT>
__global__ __launch_bounds__(512, 4) void gemm_p(
    const bf16_t* __restrict__ A, const bf16_t* __restrict__ BT,
    const float* __restrict__ bias, OutT* __restrict__ C,
    int M, int N, int K, int ntiles) {
  extern __shared__ char smem[];
  const int tid = threadIdx.x;
  const int wv = tid >> 6, ln = tid & 63;
  const int lr = ln & 15, lg = ln >> 4;
  const int wm = wv >> 1, wn = wv & 1;

  const int nx = N >> 7;
  const int chunk = ntiles >> 3;

  const int lrow = wv * 16 + (ln >> 2);
  const int lcol = ((ln & 3) << 3) ^ ((ln & 32) >> 1);
  const size_t skA = (size_t)128 * K;
  const int sw = (lr & 8) << 2;
  const int aoff = (wm * 64 + lr) * 64 + ((lg * 16) ^ sw);
  const int boff = (wn * 64 + lr) * 64 + ((lg * 16) ^ sw);
  const int NT = K >> 5;

  for (int tt = blockIdx.x; tt < ntiles; tt += gridDim.x) {
    const int wg = (tt & 7) * chunk + (tt >> 3);
    const int m0 = (wg / nx) * 256, n0 = (wg % nx) * 128;

    const bf16_t* gA = A + (size_t)(m0 + lrow) * K + lcol;
    const bf16_t* gB = BT + (size_t)(n0 + lrow) * K + lcol;

    f32x4 acc[4][4] = {};

#pragma unroll
    for (int t = 0; t < 2; ++t) {
      char* d = smem + t * 24576 + wv * 1024;
      __builtin_amdgcn_global_load_lds((const AS1 void*)(gA + t * 32), (AS3 void*)(d), 16, 0, 0);
      __builtin_amdgcn_global_load_lds((const AS1 void*)(gA + skA + t * 32), (AS3 void*)(d + 8192), 16, 0, 0);
      __builtin_amdgcn_global_load_lds((const AS1 void*)(gB + t * 32), (AS3 void*)(d + 16384), 16, 0, 0);
    }
    asm volatile("s_waitcnt vmcnt(3)" ::: "memory");
    __builtin_amdgcn_s_barrier();

    int slot = 0, nslot = 2;
    int t = 0;
    for (; t < NT - 2; ++t) {
      tile_step<true, 3>(smem + slot * 24576, aoff, boff, gA, gB, (t + 2) * 32,
                         skA, smem + nslot * 24576 + wv * 1024, acc);
      slot = (slot == 2) ? 0 : slot + 1;
      nslot = (nslot == 2) ? 0 : nslot + 1;
    }
    tile_step<false, 0>(smem + slot * 24576, aoff, boff, gA, gB, 0, skA, smem, acc);
    slot = (slot == 2) ? 0 : slot + 1;
    tile_step<false, -1>(smem + slot * 24576, aoff, boff, gA, gB, 0, skA, smem, acc);

#pragma unroll
    for (int mi = 0; mi < 4; ++mi)
#pragma unroll
      for (int ni = 0; ni < 4; ++ni) {
        const int col = n0 + wn * 64 + ni * 16 + lr;
        const float bv = bias[col];
#pragma unroll
        for (int i = 0; i < 4; ++i) {
          const int row = m0 + wm * 64 + mi * 16 + lg * 4 + i;
          C[(size_t)row * N + col] = (OutT)(acc[mi][ni][i] + bv);
        }
      }
  }
}

// ---------------- flash attention: causal, 32 heads, d=128, QBLK=128 ----------------
// R18-proven form: Vts LDS-staged, T14 async-stage split, exp2 softmax, defer-max,
// T5 setprio, balanced causal pairing (co-resident pair (bid, bid+256) -> (qt, 15-qt)).
__global__ __launch_bounds__(256, 2) void attn_fwd(
    const bf16_t* __restrict__ qkv, const bf16_t* __restrict__ vt,
    bf16_t* __restrict__ ctx) {
  __shared__ __align__(16) bf16_t Ks[64][136];
  __shared__ __align__(16) bf16_t Vts[128][72];

  const int tid = threadIdx.x;
  const int wv = tid >> 6, ln = tid & 63;
  bf16_t* Pl = &Ks[0][0] + wv * (32 * 68);

  const int bid = blockIdx.x;
  const int a = bid >> 3;
  const int hsub = a >> 4;
  const int h  = ((bid & 7) << 2) + hsub;
  const int qt = (hsub < 2) ? (a & 15) : 15 - (a & 15);
  const int q0 = qt * 128;
  const int lr = ln & 15, lg = ln >> 4;
  const int rbase = q0 + 32 * wv;

  bf16x8 qf[2][4];
#pragma unroll
  for (int rg = 0; rg < 2; ++rg)
#pragma unroll
    for (int kk = 0; kk < 4; ++kk) {
      bf16x8 r = *(const bf16x8*)(qkv + (size_t)(rbase + 16 * rg + lr) * N3 + h * HD + kk * 32 + lg * 8);
#pragma unroll
      for (int j = 0; j < 8; ++j) r[j] = (bf16_t)((float)r[j] * SC2);
      qf[rg][kk] = r;
    }

  f32x4 oacc[2][8] = {};
  float mrow[2][4], psum[2][4];
#pragma unroll
  for (int rg = 0; rg < 2; ++rg)
#pragma unroll
    for (int i = 0; i < 4; ++i) { mrow[rg][i] = -INFINITY; psum[rg][i] = 0.f; }

  const int k_r = tid >> 4, k_c = (tid & 15) * 8;
  const int v_r = tid >> 3, v_c = (tid & 7) * 8;
  bf16x8 kr[4], vr[4];

#pragma unroll
  for (int it = 0; it < 4; ++it) {
    kr[it] = *(const bf16x8*)(qkv + (size_t)(k_r + it * 16) * N3 + HID + h * HD + k_c);
    vr[it] = *(const bf16x8*)(vt + (size_t)(h * HD + v_r + it * 32) * S_ + v_c);
  }

  const int ntiles = 2 * qt + 2;
  for (int t = 0; t < ntiles; ++t) {
    const int kv0 = t * 64;
    const int kvn = (t + 1 < ntiles) ? kv0 + 64 : 0;
    __syncthreads();
#pragma unroll
    for (int it = 0; it < 4; ++it) {
      *(bf16x8*)&Ks[k_r + it * 16][k_c] = kr[it];
      *(bf16x8*)&Vts[v_r + it * 32][v_c] = vr[it];
    }
#pragma unroll
    for (int it = 0; it < 4; ++it) {
      kr[it] = *(const bf16x8*)(qkv + (size_t)(kvn + k_r + it * 16) * N3 + HID + h * HD + k_c);
      vr[it] = *(const bf16x8*)(vt + (size_t)(h * HD + v_r + it * 32) * S_ + kvn + v_c);
    }
    __syncthreads();

    f32x4 sacc[2][4] = {};
    __builtin_amdgcn_s_setprio(1);
#pragma unroll
    for (int kk = 0; kk < 4; ++kk)
#pragma unroll
      for (int ni = 0; ni < 4; ++ni) {
        bf16x8 kf = *(const bf16x8*)&Ks[16 * ni + lr][kk * 32 + lg * 8];
        sacc[0][ni] = __builtin_amdgcn_mfma_f32_16x16x32_bf16(qf[0][kk], kf, sacc[0][ni], 0, 0, 0);
        sacc[1][ni] = __builtin_amdgcn_mfma_f32_16x16x32_bf16(qf[1][kk], kf, sacc[1][ni], 0, 0, 0);
      }
    __builtin_amdgcn_s_setprio(0);

    float p[2][4][4];
    float mx[2][4];
    bool grow = false;
#pragma unroll
    for (int rg = 0; rg < 2; ++rg) {
      const bool needmask = (kv0 + 63 > rbase + 16 * rg);
#pragma unroll
      for (int i = 0; i < 4; ++i) {
        const int row = rbase + 16 * rg + lg * 4 + i;
        float m_ = -INFINITY;
#pragma unroll
        for (int ni = 0; ni < 4; ++ni) {
          float s = sacc[rg][ni][i];
          if (needmask && (kv0 + 16 * ni + lr > row)) s = -INFINITY;
          p[rg][ni][i] = s;
          m_ = fmaxf(m_, s);
        }
        m_ = fmaxf(m_, __shfl_xor(m_, 1, 64));
        m_ = fmaxf(m_, __shfl_xor(m_, 2, 64));
        m_ = fmaxf(m_, __shfl_xor(m_, 4, 64));
        m_ = fmaxf(m_, __shfl_xor(m_, 8, 64));
        mx[rg][i] = m_;
        grow |= (m_ > mrow[rg][i] + THR);
      }
    }
    if (__any(grow)) {
#pragma unroll
      for (int rg = 0; rg < 2; ++rg) {
        float alpha[4];
#pragma unroll
        for (int i = 0; i < 4; ++i) {
          const float mn = fmaxf(mrow[rg][i], mx[rg][i]);
          alpha[i] = exp2f(mrow[rg][i] - mn);
          mrow[rg][i] = mn;
          psum[rg][i] *= alpha[i];
        }
#pragma unroll
        for (int nf = 0; nf < 8; ++nf)
#pragma unroll
          for (int i = 0; i < 4; ++i) oacc[rg][nf][i] *= alpha[i];
      }
    }
#pragma unroll
    for (int rg = 0; rg < 2; ++rg)
#pragma unroll
      for (int i = 0; i < 4; ++i) {
        float ps = 0.f;
#pragma unroll
        for (int ni = 0; ni < 4; ++ni) {
          float e = exp2f(p[rg][ni][i] - mrow[rg][i]);
          p[rg][ni][i] = e;
          ps += e;
        }
        psum[rg][i] += ps;
      }

    __syncthreads();

#pragma unroll
    for (int rg = 0; rg < 2; ++rg)
#pragma unroll
      for (int ni = 0; ni < 4; ++ni)
#pragma unroll
        for (int i = 0; i < 4; ++i)
          Pl[(16 * rg + lg * 4 + i) * 68 + 16 * ni + lr] = (bf16_t)p[rg][ni][i];

#pragma unroll
    for (int kk2 = 0; kk2 < 2; ++kk2) {
      bf16x8 pf0 = *(const bf16x8*)&Pl[lr * 68 + kk2 * 32 + lg * 8];
      bf16x8 pf1 = *(const bf16x8*)&Pl[(16 + lr) * 68 + kk2 * 32 + lg * 8];
      __builtin_amdgcn_s_setprio(1);
#pragma unroll
      for (int nf = 0; nf < 8; ++nf) {
        bf16x8 vf = *(const bf16x8*)&Vts[16 * nf + lr][kk2 * 32 + lg * 8];
        oacc[0][nf] = __builtin_amdgcn_mfma_f32_16x16x32_bf16(pf0, vf, oacc[0][nf], 0, 0, 0);
        oacc[1][nf] = __builtin_amdgcn_mfma_f32_16x16x32_bf16(pf1, vf, oacc[1][nf], 0, 0, 0);
      }
      __builtin_amdgcn_s_setprio(0);
    }
  }

#pragma unroll
  for (int rg = 0; rg < 2; ++rg) {
#pragma unroll
    for (int i = 0; i < 4; ++i) {
      float s = psum[rg][i];
      s += __shfl_xor(s, 1, 64);
      s += __shfl_xor(s, 2, 64);
      s += __shfl_xor(s, 4, 64);
      s += __shfl_xor(s, 8, 64);
      psum[rg][i] = 1.f / s;
    }
#pragma unroll
    for (int nf = 0; nf < 8; ++nf)
#pragma unroll
      for (int i = 0; i < 4; ++i) {
        int row = rbase + 16 * rg + lg * 4 + i;
        int col = h * HD + 16 * nf + lr;
        ctx[(size_t)row * HID + col] = (bf16_t)(oacc[rg][nf][i] * psum[rg][i]);
      }
  }
}

// ---------------- launcher ----------------
extern "C" void kernel_launch(void* const* d_in, const int* in_sizes, int n_in,
                              void* d_out, int out_size, void* d_ws, size_t ws_size,
                              hipStream_t stream) {
  const float* x    = (const float*)d_in[0];
  const float* wqkv = (const float*)d_in[1];
  const float* bqkv = (const float*)d_in[2];
  const float* ow   = (const float*)d_in[3];
  const float* ob   = (const float*)d_in[4];
  float* out = (float*)d_out;

  char* w = (char*)d_ws;
  bf16_t* xb    = (bf16_t*)(w);                          // S*HID       bf16 (16 MB)
  bf16_t* wqkvT = (bf16_t*)(w + (size_t)16777216);       // N3*HID      bf16 (100.7 MB)
  bf16_t* qkv   = (bf16_t*)(w + (size_t)117440512);      // S*N3        bf16 (50.3 MB)
  bf16_t* vt    = (bf16_t*)(w + (size_t)167772160);      // NH*HD*S     bf16 (16 MB)
  bf16_t* ctx   = (bf16_t*)(w + (size_t)184549376);      // S*HID       bf16 (16 MB)
  bf16_t* owT   = (bf16_t*)(w + (size_t)201326592);      // HID*HID     bf16 (33.6 MB)

  (void)in_sizes; (void)n_in; (void)out_size; (void)ws_size;

  cvt_f32_bf16<<<(S_ * HID / 4 + 255) / 256, 256, 0, stream>>>(x, xb, S_ * HID / 4);
  transcvt64<<<dim3(N3 / 64, HID / 64), 256, 0, stream>>>(wqkv, wqkvT, HID, N3);
  transcvt64<<<dim3(HID / 64, HID / 64), 256, 0, stream>>>(ow, owT, HID, HID);
  // QKV projection: 768 tiles, persistent 512 x 256thr blocks (2/CU, 3 tiles/CU)
  gemm_w<<<512, 256, 73728, stream>>>(xb, wqkvT, bqkv, qkv, S_, N3, HID,
                                      (S_ / 256) * (N3 / 128));
  vtrans<<<dim3(S_ / 32, HD / 32, NH), dim3(32, 8), 0, stream>>>(qkv, vt);
  // attention: QBLK=128, grid 512, 2 blocks/CU, balanced causal pairing
  attn_fwd<<<(S_ / 128) * NH, 256, 0, stream>>>(qkv, vt, ctx);
  // out projection: 256 tiles, 256 x 512thr blocks (1/CU, 1 tile each)
  gemm_p<float><<<256, 512, 73728, stream>>>(ctx, owT, ob, out, S_, HID, HID,
                                             (S_ / 256) * (HID / 128));
}

// Round 20
// 480.618 us; speedup vs baseline: 1.0096x; 1.0096x over previous
//
#include <hip/hip_runtime.h>
#include <hip/hip_bf16.h>
#include <math.h>

typedef __bf16 bf16_t;
typedef __bf16 bf16x8 __attribute__((ext_vector_type(8)));
typedef float f32x4 __attribute__((ext_vector_type(4)));

#define AS1 __attribute__((address_space(1)))
#define AS3 __attribute__((address_space(3)))

static constexpr int S_  = 2048;
static constexpr int HID = 4096;
static constexpr int NH  = 32;
static constexpr int HD  = 128;
static constexpr int N3  = 3 * HID;           // 12288
static constexpr float SC2 = 0.12751674581f;  // (1/sqrt(128)) * log2(e)
static constexpr float THR = 11.0f;           // defer-max threshold

// ---------------- fp32 -> bf16 convert (vectorized) ----------------
__global__ void cvt_f32_bf16(const float* __restrict__ in, bf16_t* __restrict__ out, int n4) {
  int i = blockIdx.x * blockDim.x + threadIdx.x;
  if (i >= n4) return;
  float4 v = ((const float4*)in)[i];
  union { bf16_t h[4]; short4 s4; } u;
  u.h[0] = (bf16_t)v.x; u.h[1] = (bf16_t)v.y; u.h[2] = (bf16_t)v.z; u.h[3] = (bf16_t)v.w;
  ((short4*)out)[i] = u.s4;
}

// ------- transpose + convert: in[R][C] f32 -> out[C][R] bf16, 64x64 tile -------
__global__ __launch_bounds__(256) void transcvt64(
    const float* __restrict__ in, bf16_t* __restrict__ out, int R, int C) {
  __shared__ float t[64][65];
  const int r0 = blockIdx.y * 64, c0 = blockIdx.x * 64;
  const int tid = threadIdx.x;
  const int rr = tid >> 4, c4 = (tid & 15) * 4;
#pragma unroll
  for (int it = 0; it < 4; ++it) {
    float4 v = *(const float4*)&in[(size_t)(r0 + rr + it * 16) * C + c0 + c4];
    t[rr + it * 16][c4 + 0] = v.x;
    t[rr + it * 16][c4 + 1] = v.y;
    t[rr + it * 16][c4 + 2] = v.z;
    t[rr + it * 16][c4 + 3] = v.w;
  }
  __syncthreads();
  const int cc = tid >> 3, r8 = (tid & 7) * 8;
#pragma unroll
  for (int it = 0; it < 2; ++it) {
    const int c = cc + it * 32;
    bf16x8 w;
#pragma unroll
    for (int j = 0; j < 8; ++j) w[j] = (bf16_t)t[r8 + j][c];
    *(bf16x8*)&out[(size_t)(c0 + c) * R + r0 + r8] = w;
  }
}

// ------- per-head V transpose: qkv[s][2*HID + h*HD + d] -> vt[(h*HD+d)*S + s] -------
__global__ void vtrans(const bf16_t* __restrict__ qkv, bf16_t* __restrict__ vt) {
  __shared__ bf16_t t[32][33];
  int h = blockIdx.z;
  int s0 = blockIdx.x * 32, d0 = blockIdx.y * 32;
  int tx = threadIdx.x, ty = threadIdx.y;
#pragma unroll
  for (int i = 0; i < 32; i += 8)
    t[ty + i][tx] = qkv[(size_t)(s0 + ty + i) * N3 + 2 * HID + h * HD + d0 + tx];
  __syncthreads();
#pragma unroll
  for (int i = 0; i < 32; i += 8)
    vt[(size_t)(h * HD + d0 + ty + i) * S_ + s0 + tx] = t[tx][ty + i];
}

// ====== gemm_w: 256x128 tile, 4 waves (2Mx2N) of 128x64, ring-3, persistent ======
// R18-proven body.  R20: XCD chunk reshaped 1x96 -> 8x12 (m-fastest within an
// n-panel): consecutive tiles share one 1MB B-panel (L2-resident across its 8
// users); each B-panel touched by exactly ONE XCD -> B fetched ~once instead of 8x.
template <bool STG, int VMC>
__device__ __forceinline__ void wstep(
    const char* slot, int aoff, int boff,
    const bf16_t* gA, const bf16_t* gB, int kst, size_t row64,
    char* stgA, char* stgB, f32x4 (&acc)[8][4]) {
  bf16x8 a[8], b[4];
#pragma unroll
  for (int mi = 0; mi < 8; ++mi) a[mi] = *(const bf16x8*)(slot + aoff + mi * 1024);
#pragma unroll
  for (int ni = 0; ni < 4; ++ni) b[ni] = *(const bf16x8*)(slot + 16384 + boff + ni * 1024);
  if constexpr (STG) {
#pragma unroll
    for (int i = 0; i < 4; ++i)
      __builtin_amdgcn_global_load_lds((const AS1 void*)(gA + i * row64 + kst),
                                       (AS3 void*)(stgA + i * 4096), 16, 0, 0);
#pragma unroll
    for (int j = 0; j < 2; ++j)
      __builtin_amdgcn_global_load_lds((const AS1 void*)(gB + j * row64 + kst),
                                       (AS3 void*)(stgB + j * 4096), 16, 0, 0);
  }
  if constexpr (VMC == 6)      asm volatile("s_waitcnt vmcnt(6)" ::: "memory");
  else if constexpr (VMC == 0) asm volatile("s_waitcnt vmcnt(0)" ::: "memory");
  asm volatile("s_waitcnt lgkmcnt(0)" ::: "memory");  // own reads COMPLETE pre-barrier
  __builtin_amdgcn_s_barrier();
  __builtin_amdgcn_s_setprio(1);
#pragma unroll
  for (int mi = 0; mi < 8; ++mi)
#pragma unroll
    for (int ni = 0; ni < 4; ++ni)
      acc[mi][ni] = __builtin_amdgcn_mfma_f32_16x16x32_bf16(a[mi], b[ni], acc[mi][ni], 0, 0, 0);
  __builtin_amdgcn_s_setprio(0);
}

__global__ __launch_bounds__(256, 2) void gemm_w(
    const bf16_t* __restrict__ A, const bf16_t* __restrict__ BT,
    const float* __restrict__ bias, bf16_t* __restrict__ C,
    int M, int N, int K, int ntiles) {
  extern __shared__ char smem[];
  const int tid = threadIdx.x;
  const int wv = tid >> 6, ln = tid & 63;
  const int lr = ln & 15, lg = ln >> 4;
  const int wm = wv >> 1, wn = wv & 1;

  const int ncolsX = ntiles >> 6;  // n-panels per XCD = chunk/8 (M = 8 m-tiles)

  const int lrow = wv * 16 + (ln >> 2);
  const int lcol = ((ln & 3) << 3) ^ ((ln & 32) >> 1);
  const size_t row64 = (size_t)64 * K;
  const int sw = (lr & 8) << 2;
  const int aoff = (wm * 128 + lr) * 64 + ((lg * 16) ^ sw);
  const int boff = (wn * 64 + lr) * 64 + ((lg * 16) ^ sw);
  const int NT = K >> 5;

  for (int tt = blockIdx.x; tt < ntiles; tt += gridDim.x) {
    // XCD x gets n-panels [x*ncolsX, (x+1)*ncolsX); m-fastest within a panel
    const int x = tt & 7, local = tt >> 3;
    const int m0 = (local & 7) * 256;
    const int n0 = (x * ncolsX + (local >> 3)) * 128;

    const bf16_t* gA = A + (size_t)(m0 + lrow) * K + lcol;
    const bf16_t* gB = BT + (size_t)(n0 + lrow) * K + lcol;

    f32x4 acc[8][4] = {};

#pragma unroll
    for (int t = 0; t < 2; ++t) {
      char* dA = smem + t * 24576 + wv * 1024;
      char* dB = dA + 16384;
#pragma unroll
      for (int i = 0; i < 4; ++i)
        __builtin_amdgcn_global_load_lds((const AS1 void*)(gA + i * row64 + t * 32),
                                         (AS3 void*)(dA + i * 4096), 16, 0, 0);
#pragma unroll
      for (int j = 0; j < 2; ++j)
        __builtin_amdgcn_global_load_lds((const AS1 void*)(gB + j * row64 + t * 32),
                                         (AS3 void*)(dB + j * 4096), 16, 0, 0);
    }
    asm volatile("s_waitcnt vmcnt(6)" ::: "memory");
    __builtin_amdgcn_s_barrier();

    int slot = 0, nslot = 2;
    int t = 0;
    for (; t < NT - 2; ++t) {
      char* sb = smem + nslot * 24576 + wv * 1024;
      wstep<true, 6>(smem + slot * 24576, aoff, boff, gA, gB, (t + 2) * 32,
                     row64, sb, sb + 16384, acc);
      slot = (slot == 2) ? 0 : slot + 1;
      nslot = (nslot == 2) ? 0 : nslot + 1;
    }
    wstep<false, 0>(smem + slot * 24576, aoff, boff, gA, gB, 0, row64, smem, smem, acc);
    slot = (slot == 2) ? 0 : slot + 1;
    wstep<false, -1>(smem + slot * 24576, aoff, boff, gA, gB, 0, row64, smem, smem, acc);

#pragma unroll
    for (int mi = 0; mi < 8; ++mi)
#pragma unroll
      for (int ni = 0; ni < 4; ++ni) {
        const int col = n0 + wn * 64 + ni * 16 + lr;
        const float bv = bias[col];
#pragma unroll
        for (int i = 0; i < 4; ++i) {
          const int row = m0 + wm * 128 + mi * 16 + lg * 4 + i;
          C[(size_t)row * N + col] = (bf16_t)(acc[mi][ni][i] + bv);
        }
      }
  }
}

// ====== 256x128-tile GEMM, 8 waves of 64x64, ring-3, persistent (out-proj) ======
template <bool STG, int VMC>
__device__ __forceinline__ void tile_step(
    const char* slot, int aoff, int boff,
    const bf16_t* gA, const bf16_t* gB, int kst, size_t skA,
    char* stg_dst, f32x4 (&acc)[4][4]) {
  bf16x8 a[4], b[4];
#pragma unroll
  for (int mi = 0; mi < 4; ++mi) a[mi] = *(const bf16x8*)(slot + aoff + mi * 1024);
#pragma unroll
  for (int ni = 0; ni < 4; ++ni) b[ni] = *(const bf16x8*)(slot + 16384 + boff + ni * 1024);
  if constexpr (STG) {
    __builtin_amdgcn_global_load_lds((const AS1 void*)(gA + kst), (AS3 void*)(stg_dst), 16, 0, 0);
    __builtin_amdgcn_global_load_lds((const AS1 void*)(gA + skA + kst), (AS3 void*)(stg_dst + 8192), 16, 0, 0);
    __builtin_amdgcn_global_load_lds((const AS1 void*)(gB + kst), (AS3 void*)(stg_dst + 16384), 16, 0, 0);
  }
  if constexpr (VMC == 3)      asm volatile("s_waitcnt vmcnt(3)" ::: "memory");
  else if constexpr (VMC == 0) asm volatile("s_waitcnt vmcnt(0)" ::: "memory");
  asm volatile("s_waitcnt lgkmcnt(0)" ::: "memory");
  __builtin_amdgcn_s_barrier();
  __builtin_amdgcn_s_setprio(1);
#pragma unroll
  for (int mi = 0; mi < 4; ++mi)
#pragma unroll
    for (int ni = 0; ni < 4; ++ni)
      acc[mi][ni] = __builtin_amdgcn_mfma_f32_16x16x32_bf16(a[mi], b[ni], acc[mi][ni], 0, 0, 0);
  __builtin_amdgcn_s_setprio(0);
}

template <typename OutT>
__global__ __launch_bounds__(512, 4) void gemm_p(
    const bf16_t* __restrict__ A, const bf16_t* __restrict__ BT,
    const float* __restrict__ bias, OutT* __restrict__ C,
    int M, int N, int K, int ntiles) {
  extern __shared__ char smem[];
  const int tid = threadIdx.x;
  const int wv = tid >> 6, ln = tid & 63;
  const int lr = ln & 15, lg = ln >> 4;
  const int wm = wv >> 1, wn = wv & 1;

  const int ncolsX = ntiles >> 6;  // n-panels per XCD (M = 8 m-tiles)

  const int lrow = wv * 16 + (ln >> 2);
  const int lcol = ((ln & 3) << 3) ^ ((ln & 32) >> 1);
  const size_t skA = (size_t)128 * K;
  const int sw = (lr & 8) << 2;
  const int aoff = (wm * 64 + lr) * 64 + ((lg * 16) ^ sw);
  const int boff = (wn * 64 + lr) * 64 + ((lg * 16) ^ sw);
  const int NT = K >> 5;

  for (int tt = blockIdx.x; tt < ntiles; tt += gridDim.x) {
    const int x = tt & 7, local = tt >> 3;
    const int m0 = (local & 7) * 256;
    const int n0 = (x * ncolsX + (local >> 3)) * 128;

    const bf16_t* gA = A + (size_t)(m0 + lrow) * K + lcol;
    const bf16_t* gB = BT + (size_t)(n0 + lrow) * K + lcol;

    f32x4 acc[4][4] = {};

#pragma unroll
    for (int t = 0; t < 2; ++t) {
      char* d = smem + t * 24576 + wv * 1024;
      __builtin_amdgcn_global_load_lds((const AS1 void*)(gA + t * 32), (AS3 void*)(d), 16, 0, 0);
      __builtin_amdgcn_global_load_lds((const AS1 void*)(gA + skA + t * 32), (AS3 void*)(d + 8192), 16, 0, 0);
      __builtin_amdgcn_global_load_lds((const AS1 void*)(gB + t * 32), (AS3 void*)(d + 16384), 16, 0, 0);
    }
    asm volatile("s_waitcnt vmcnt(3)" ::: "memory");
    __builtin_amdgcn_s_barrier();

    int slot = 0, nslot = 2;
    int t = 0;
    for (; t < NT - 2; ++t) {
      tile_step<true, 3>(smem + slot * 24576, aoff, boff, gA, gB, (t + 2) * 32,
                         skA, smem + nslot * 24576 + wv * 1024, acc);
      slot = (slot == 2) ? 0 : slot + 1;
      nslot = (nslot == 2) ? 0 : nslot + 1;
    }
    tile_step<false, 0>(smem + slot * 24576, aoff, boff, gA, gB, 0, skA, smem, acc);
    slot = (slot == 2) ? 0 : slot + 1;
    tile_step<false, -1>(smem + slot * 24576, aoff, boff, gA, gB, 0, skA, smem, acc);

#pragma unroll
    for (int mi = 0; mi < 4; ++mi)
#pragma unroll
      for (int ni = 0; ni < 4; ++ni) {
        const int col = n0 + wn * 64 + ni * 16 + lr;
        const float bv = bias[col];
#pragma unroll
        for (int i = 0; i < 4; ++i) {
          const int row = m0 + wm * 64 + mi * 16 + lg * 4 + i;
          C[(size_t)row * N + col] = (OutT)(acc[mi][ni][i] + bv);
        }
      }
  }
}

// ---------------- flash attention: causal, 32 heads, d=128, QBLK=128 ----------------
// R18-proven form: Vts LDS-staged, T14 async-stage split, exp2 softmax, defer-max,
// T5 setprio, balanced causal pairing (co-resident pair (bid, bid+256) -> (qt, 15-qt)).
__global__ __launch_bounds__(256, 2) void attn_fwd(
    const bf16_t* __restrict__ qkv, const bf16_t* __restrict__ vt,
    bf16_t* __restrict__ ctx) {
  __shared__ __align__(16) bf16_t Ks[64][136];
  __shared__ __align__(16) bf16_t Vts[128][72];

  const int tid = threadIdx.x;
  const int wv = tid >> 6, ln = tid & 63;
  bf16_t* Pl = &Ks[0][0] + wv * (32 * 68);

  const int bid = blockIdx.x;
  const int a = bid >> 3;
  const int hsub = a >> 4;
  const int h  = ((bid & 7) << 2) + hsub;
  const int qt = (hsub < 2) ? (a & 15) : 15 - (a & 15);
  const int q0 = qt * 128;
  const int lr = ln & 15, lg = ln >> 4;
  const int rbase = q0 + 32 * wv;

  bf16x8 qf[2][4];
#pragma unroll
  for (int rg = 0; rg < 2; ++rg)
#pragma unroll
    for (int kk = 0; kk < 4; ++kk) {
      bf16x8 r = *(const bf16x8*)(qkv + (size_t)(rbase + 16 * rg + lr) * N3 + h * HD + kk * 32 + lg * 8);
#pragma unroll
      for (int j = 0; j < 8; ++j) r[j] = (bf16_t)((float)r[j] * SC2);
      qf[rg][kk] = r;
    }

  f32x4 oacc[2][8] = {};
  float mrow[2][4], psum[2][4];
#pragma unroll
  for (int rg = 0; rg < 2; ++rg)
#pragma unroll
    for (int i = 0; i < 4; ++i) { mrow[rg][i] = -INFINITY; psum[rg][i] = 0.f; }

  const int k_r = tid >> 4, k_c = (tid & 15) * 8;
  const int v_r = tid >> 3, v_c = (tid & 7) * 8;
  bf16x8 kr[4], vr[4];

#pragma unroll
  for (int it = 0; it < 4; ++it) {
    kr[it] = *(const bf16x8*)(qkv + (size_t)(k_r + it * 16) * N3 + HID + h * HD + k_c);
    vr[it] = *(const bf16x8*)(vt + (size_t)(h * HD + v_r + it * 32) * S_ + v_c);
  }

  const int ntiles = 2 * qt + 2;
  for (int t = 0; t < ntiles; ++t) {
    const int kv0 = t * 64;
    const int kvn = (t + 1 < ntiles) ? kv0 + 64 : 0;
    __syncthreads();
#pragma unroll
    for (int it = 0; it < 4; ++it) {
      *(bf16x8*)&Ks[k_r + it * 16][k_c] = kr[it];
      *(bf16x8*)&Vts[v_r + it * 32][v_c] = vr[it];
    }
#pragma unroll
    for (int it = 0; it < 4; ++it) {
      kr[it] = *(const bf16x8*)(qkv + (size_t)(kvn + k_r + it * 16) * N3 + HID + h * HD + k_c);
      vr[it] = *(const bf16x8*)(vt + (size_t)(h * HD + v_r + it * 32) * S_ + kvn + v_c);
    }
    __syncthreads();

    f32x4 sacc[2][4] = {};
    __builtin_amdgcn_s_setprio(1);
#pragma unroll
    for (int kk = 0; kk < 4; ++kk)
#pragma unroll
      for (int ni = 0; ni < 4; ++ni) {
        bf16x8 kf = *(const bf16x8*)&Ks[16 * ni + lr][kk * 32 + lg * 8];
        sacc[0][ni] = __builtin_amdgcn_mfma_f32_16x16x32_bf16(qf[0][kk], kf, sacc[0][ni], 0, 0, 0);
        sacc[1][ni] = __builtin_amdgcn_mfma_f32_16x16x32_bf16(qf[1][kk], kf, sacc[1][ni], 0, 0, 0);
      }
    __builtin_amdgcn_s_setprio(0);

    float p[2][4][4];
    float mx[2][4];
    bool grow = false;
#pragma unroll
    for (int rg = 0; rg < 2; ++rg) {
      const bool needmask = (kv0 + 63 > rbase + 16 * rg);
#pragma unroll
      for (int i = 0; i < 4; ++i) {
        const int row = rbase + 16 * rg + lg * 4 + i;
        float m_ = -INFINITY;
#pragma unroll
        for (int ni = 0; ni < 4; ++ni) {
          float s = sacc[rg][ni][i];
          if (needmask && (kv0 + 16 * ni + lr > row)) s = -INFINITY;
          p[rg][ni][i] = s;
          m_ = fmaxf(m_, s);
        }
        m_ = fmaxf(m_, __shfl_xor(m_, 1, 64));
        m_ = fmaxf(m_, __shfl_xor(m_, 2, 64));
        m_ = fmaxf(m_, __shfl_xor(m_, 4, 64));
        m_ = fmaxf(m_, __shfl_xor(m_, 8, 64));
        mx[rg][i] = m_;
        grow |= (m_ > mrow[rg][i] + THR);
      }
    }
    if (__any(grow)) {
#pragma unroll
      for (int rg = 0; rg < 2; ++rg) {
        float alpha[4];
#pragma unroll
        for (int i = 0; i < 4; ++i) {
          const float mn = fmaxf(mrow[rg][i], mx[rg][i]);
          alpha[i] = exp2f(mrow[rg][i] - mn);
          mrow[rg][i] = mn;
          psum[rg][i] *= alpha[i];
        }
#pragma unroll
        for (int nf = 0; nf < 8; ++nf)
#pragma unroll
          for (int i = 0; i < 4; ++i) oacc[rg][nf][i] *= alpha[i];
      }
    }
#pragma unroll
    for (int rg = 0; rg < 2; ++rg)
#pragma unroll
      for (int i = 0; i < 4; ++i) {
        float ps = 0.f;
#pragma unroll
        for (int ni = 0; ni < 4; ++ni) {
          float e = exp2f(p[rg][ni][i] - mrow[rg][i]);
          p[rg][ni][i] = e;
          ps += e;
        }
        psum[rg][i] += ps;
      }

    __syncthreads();

#pragma unroll
    for (int rg = 0; rg < 2; ++rg)
#pragma unroll
      for (int ni = 0; ni < 4; ++ni)
#pragma unroll
        for (int i = 0; i < 4; ++i)
          Pl[(16 * rg + lg * 4 + i) * 68 + 16 * ni + lr] = (bf16_t)p[rg][ni][i];

#pragma unroll
    for (int kk2 = 0; kk2 < 2; ++kk2) {
      bf16x8 pf0 = *(const bf16x8*)&Pl[lr * 68 + kk2 * 32 + lg * 8];
      bf16x8 pf1 = *(const bf16x8*)&Pl[(16 + lr) * 68 + kk2 * 32 + lg * 8];
      __builtin_amdgcn_s_setprio(1);
#pragma unroll
      for (int nf = 0; nf < 8; ++nf) {
        bf16x8 vf = *(const bf16x8*)&Vts[16 * nf + lr][kk2 * 32 + lg * 8];
        oacc[0][nf] = __builtin_amdgcn_mfma_f32_16x16x32_bf16(pf0, vf, oacc[0][nf], 0, 0, 0);
        oacc[1][nf] = __builtin_amdgcn_mfma_f32_16x16x32_bf16(pf1, vf, oacc[1][nf], 0, 0, 0);
      }
      __builtin_amdgcn_s_setprio(0);
    }
  }

#pragma unroll
  for (int rg = 0; rg < 2; ++rg) {
#pragma unroll
    for (int i = 0; i < 4; ++i) {
      float s = psum[rg][i];
      s += __shfl_xor(s, 1, 64);
      s += __shfl_xor(s, 2, 64);
      s += __shfl_xor(s, 4, 64);
      s += __shfl_xor(s, 8, 64);
      psum[rg][i] = 1.f / s;
    }
#pragma unroll
    for (int nf = 0; nf < 8; ++nf)
#pragma unroll
      for (int i = 0; i < 4; ++i) {
        int row = rbase + 16 * rg + lg * 4 + i;
        int col = h * HD + 16 * nf + lr;
        ctx[(size_t)row * HID + col] = (bf16_t)(oacc[rg][nf][i] * psum[rg][i]);
      }
  }
}

// ---------------- launcher ----------------
extern "C" void kernel_launch(void* const* d_in, const int* in_sizes, int n_in,
                              void* d_out, int out_size, void* d_ws, size_t ws_size,
                              hipStream_t stream) {
  const float* x    = (const float*)d_in[0];
  const float* wqkv = (const float*)d_in[1];
  const float* bqkv = (const float*)d_in[2];
  const float* ow   = (const float*)d_in[3];
  const float* ob   = (const float*)d_in[4];
  float* out = (float*)d_out;

  char* w = (char*)d_ws;
  bf16_t* xb    = (bf16_t*)(w);                          // S*HID       bf16 (16 MB)
  bf16_t* wqkvT = (bf16_t*)(w + (size_t)16777216);       // N3*HID      bf16 (100.7 MB)
  bf16_t* qkv   = (bf16_t*)(w + (size_t)117440512);      // S*N3        bf16 (50.3 MB)
  bf16_t* vt    = (bf16_t*)(w + (size_t)167772160);      // NH*HD*S     bf16 (16 MB)
  bf16_t* ctx   = (bf16_t*)(w + (size_t)184549376);      // S*HID       bf16 (16 MB)
  bf16_t* owT   = (bf16_t*)(w + (size_t)201326592);      // HID*HID     bf16 (33.6 MB)

  (void)in_sizes; (void)n_in; (void)out_size; (void)ws_size;

  cvt_f32_bf16<<<(S_ * HID / 4 + 255) / 256, 256, 0, stream>>>(x, xb, S_ * HID / 4);
  transcvt64<<<dim3(N3 / 64, HID / 64), 256, 0, stream>>>(wqkv, wqkvT, HID, N3);
  transcvt64<<<dim3(HID / 64, HID / 64), 256, 0, stream>>>(ow, owT, HID, HID);
  // QKV projection: 768 tiles, persistent 512 blocks; per-XCD 8m x 12n chunks
  gemm_w<<<512, 256, 73728, stream>>>(xb, wqkvT, bqkv, qkv, S_, N3, HID,
                                      (S_ / 256) * (N3 / 128));
  vtrans<<<dim3(S_ / 32, HD / 32, NH), dim3(32, 8), 0, stream>>>(qkv, vt);
  // attention: QBLK=128, grid 512, 2 blocks/CU, balanced causal pairing
  attn_fwd<<<(S_ / 128) * NH, 256, 0, stream>>>(qkv, vt, ctx);
  // out projection: 256 tiles, 256 blocks; per-XCD 8m x 4n chunks
  gemm_p<float><<<256, 512, 73728, stream>>>(ctx, owT, ob, out, S_, HID, HID,
                                             (S_ / 256) * (HID / 128));
}